// Round 1
// baseline (3638.403 us; speedup 1.0000x reference)
//
#include <hip/hip_runtime.h>
#include <math.h>

// ---------------- constants ----------------
#define NB 4
#define NN 8192
#define ROWS (NB*NN)          // 32768
#define DIMC 512
#define HEADS 8
#define DH 64
#define DT 128
#define DELTA 64
#define FF 2048

// workspace layout (floats)
#define OFF_H      ((size_t)0)                  // 16,777,216  (LN1 out, then LN2 out)
#define OFF_K      (OFF_H + (size_t)ROWS*DIMC)  // 16,777,216  (k -> attn -> ff mid)
#define OFF_DELTA  (OFF_K + (size_t)ROWS*DIMC)  // 2,097,152
#define OFF_Y      (OFF_DELTA + (size_t)ROWS*DELTA) // 512
#define OFF_BB     (OFF_Y + 512)                // 2048
#define OFF_WCOMP  (OFF_BB + 2048)              // 262,144
#define OFF_PM     (OFF_WCOMP + 262144)         // 4*64*512 = 131,072
#define OFF_PS     (OFF_PM + 131072)            // 131,072
#define OFF_M      (OFF_PS + 131072)            // 2048
#define OFF_SINV   (OFF_M + 2048)               // 2048
#define OFF_CTX    (OFF_SINV + 2048)            // 131,072

static __device__ __forceinline__ float gelu_tanh(float x) {
    float t = tanhf(0.7978845608028654f * (x + 0.044715f * x * x * x));
    return 0.5f * x * (1.0f + t);
}

// ---------------- tiny kernels ----------------
__global__ void y_kernel(const float* __restrict__ dt, const float* __restrict__ yyw,
                         const float* __restrict__ yyb, float* __restrict__ y_ws,
                         float* __restrict__ y_out) {
    int idx = blockIdx.x * 128 + threadIdx.x;   // 512
    int b = idx >> 7, j = idx & 127;
    float acc = yyb[j];
    for (int c = 0; c < DT; ++c) acc += dt[b * DT + c] * yyw[c * DT + j];
    y_ws[idx] = acc;
    y_out[idx] = acc;
}

__global__ void bb_kernel(const float* __restrict__ linxb, const float* __restrict__ catw,
                          const float* __restrict__ catb, const float* __restrict__ y,
                          float* __restrict__ bb) {
    int idx = blockIdx.x * 256 + threadIdx.x;   // 2048
    int b = idx >> 9, n = idx & 511;
    float acc = catb[n];
    for (int c = 0; c < DIMC; ++c) acc += linxb[c] * catw[(size_t)c * DIMC + n];
    const float* cw3 = catw + (size_t)(DIMC + DELTA) * DIMC;  // rows 576..703
    for (int j = 0; j < DT; ++j) acc += y[b * DT + j] * cw3[(size_t)j * DIMC + n];
    bb[idx] = acc;
}

__global__ __launch_bounds__(256) void delta_kernel(
    const float* __restrict__ pos, const float* __restrict__ mask,
    const float* __restrict__ w1, const float* __restrict__ b1,
    const float* __restrict__ w2, const float* __restrict__ b2,
    float* __restrict__ delta) {
    int lane = threadIdx.x & 63;
    size_t row = (size_t)blockIdx.x * 4 + (threadIdx.x >> 6);
    float mk = mask[row];
    float px = pos[row * 2] * mk, py = pos[row * 2 + 1] * mk;
    float nrm = sqrtf(px * px + py * py) + 1e-7f;
    float ux = px / nrm, uy = py / nrm;
    float t1 = fmaxf(ux * w1[lane] + uy * w1[64 + lane] + b1[lane], 0.0f);
    float acc = b2[lane];
    #pragma unroll
    for (int j = 0; j < 64; ++j) {
        float tv = __shfl(t1, j, 64);
        acc += tv * w2[j * 64 + lane];
    }
    delta[row * DELTA + lane] = acc;
}

__global__ __launch_bounds__(128) void ln_kernel(
    const float* __restrict__ src, float* __restrict__ dst,
    const float* __restrict__ g, const float* __restrict__ bta) {
    size_t row = blockIdx.x;
    int t = threadIdx.x;
    const float* s = src + row * DIMC;
    float4 x = *(const float4*)(s + t * 4);
    float sum = x.x + x.y + x.z + x.w;
    float sq = x.x * x.x + x.y * x.y + x.z * x.z + x.w * x.w;
    #pragma unroll
    for (int o = 32; o; o >>= 1) { sum += __shfl_down(sum, o, 64); sq += __shfl_down(sq, o, 64); }
    __shared__ float sh[4];
    if ((t & 63) == 0) { sh[(t >> 6) * 2] = sum; sh[(t >> 6) * 2 + 1] = sq; }
    __syncthreads();
    sum = sh[0] + sh[2]; sq = sh[1] + sh[3];
    float mean = sum * (1.0f / DIMC);
    float var = sq * (1.0f / DIMC) - mean * mean;
    float rstd = rsqrtf(fmaxf(var, 0.0f) + 1e-5f);
    float4 gv = *(const float4*)(g + t * 4);
    float4 bv = *(const float4*)(bta + t * 4);
    float4 o;
    o.x = (x.x - mean) * rstd * gv.x + bv.x;
    o.y = (x.y - mean) * rstd * gv.y + bv.y;
    o.z = (x.z - mean) * rstd * gv.z + bv.z;
    o.w = (x.w - mean) * rstd * gv.w + bv.w;
    *(float4*)(dst + row * DIMC + t * 4) = o;
}

// ---------------- GEMM: C[M,N] = A[M,K]@W[K,N] (+ A2[M,K2]@W2[K2,N]) + epilogue ----------------
// EPI: 0 = (+bias) store; 1 = gelu(+bias); 2 = C += acc + bias (in-place residual);
//      3 = acc + extra[(row/batch_rows)*N+col] (per-batch bias table); 4 = acc + bias + extra[idx]
template <int EPI>
__global__ __launch_bounds__(256) void gemm_f32(
    const float* __restrict__ A, const float* __restrict__ W,
    const float* __restrict__ bias, const float* __restrict__ extra,
    float* __restrict__ C, int M, int N, int K,
    const float* __restrict__ A2, const float* __restrict__ W2, int K2,
    int batch_rows) {
    __shared__ float As[32][68];
    __shared__ float Ws[32][64];
    int bm = blockIdx.y * 64, bn = blockIdx.x * 64;
    int tid = threadIdx.x;
    int tx = tid & 15, ty = tid >> 4;
    float acc[4][4] = {};
    for (int phase = 0; phase < 2; ++phase) {
        const float* Ap = phase ? A2 : A;
        const float* Wp = phase ? W2 : W;
        int Kp = phase ? K2 : K;
        if (Ap == nullptr || Kp == 0) continue;
        for (int kk = 0; kk < Kp; kk += 32) {
            #pragma unroll
            for (int i = 0; i < 2; ++i) {
                int idx = tid * 2 + i;
                int r = idx >> 3, c4 = (idx & 7) * 4;
                float4 v = *(const float4*)(Ap + (size_t)(bm + r) * Kp + kk + c4);
                As[c4 + 0][r] = v.x; As[c4 + 1][r] = v.y;
                As[c4 + 2][r] = v.z; As[c4 + 3][r] = v.w;
            }
            #pragma unroll
            for (int i = 0; i < 2; ++i) {
                int idx = tid * 2 + i;
                int r = idx >> 4, c4 = (idx & 15) * 4;
                *(float4*)&Ws[r][c4] = *(const float4*)(Wp + (size_t)(kk + r) * N + bn + c4);
            }
            __syncthreads();
            #pragma unroll
            for (int k = 0; k < 32; ++k) {
                float4 a4 = *(const float4*)&As[k][ty * 4];
                float4 b4 = *(const float4*)&Ws[k][tx * 4];
                float av[4] = {a4.x, a4.y, a4.z, a4.w};
                float bv[4] = {b4.x, b4.y, b4.z, b4.w};
                #pragma unroll
                for (int i = 0; i < 4; ++i)
                    #pragma unroll
                    for (int j = 0; j < 4; ++j)
                        acc[i][j] = fmaf(av[i], bv[j], acc[i][j]);
            }
            __syncthreads();
        }
    }
    #pragma unroll
    for (int i = 0; i < 4; ++i) {
        int row = bm + ty * 4 + i;
        #pragma unroll
        for (int j = 0; j < 4; ++j) {
            int col = bn + tx * 4 + j;
            size_t idx = (size_t)row * N + col;
            float v = acc[i][j];
            if (EPI == 0) { if (bias) v += bias[col]; C[idx] = v; }
            else if (EPI == 1) { v += bias[col]; C[idx] = gelu_tanh(v); }
            else if (EPI == 2) { v += bias[col]; C[idx] = C[idx] + v; }
            else if (EPI == 3) { v += extra[(size_t)(row / batch_rows) * N + col]; C[idx] = v; }
            else if (EPI == 4) { v += bias[col] + extra[idx]; C[idx] = v; }
        }
    }
}

// ---------------- k column-softmax stats (softmax over sequence dim) ----------------
__global__ __launch_bounds__(256) void ksm_stats1(
    const float* __restrict__ k, float* __restrict__ pm, float* __restrict__ ps) {
    int b = blockIdx.y, rb = blockIdx.x;  // 64 row blocks of 128 rows
    const float* kp = k + ((size_t)b * NN + (size_t)rb * 128) * DIMC;
    int t = threadIdx.x;
    float m0 = -1e30f, s0 = 0.f, m1 = -1e30f, s1 = 0.f;
    for (int r = 0; r < 128; ++r) {
        float x0 = kp[(size_t)r * DIMC + t];
        float x1 = kp[(size_t)r * DIMC + t + 256];
        if (x0 > m0) { s0 = s0 * __expf(m0 - x0) + 1.f; m0 = x0; } else s0 += __expf(x0 - m0);
        if (x1 > m1) { s1 = s1 * __expf(m1 - x1) + 1.f; m1 = x1; } else s1 += __expf(x1 - m1);
    }
    size_t base = ((size_t)b * 64 + rb) * DIMC;
    pm[base + t] = m0; pm[base + t + 256] = m1;
    ps[base + t] = s0; ps[base + t + 256] = s1;
}

__global__ void ksm_stats2(const float* __restrict__ pm, const float* __restrict__ ps,
                           float* __restrict__ Mst, float* __restrict__ Sinv) {
    int idx = blockIdx.x * 256 + threadIdx.x;  // 2048
    int b = idx >> 9, c = idx & 511;
    float m = -1e30f, s = 0.f;
    for (int rb = 0; rb < 64; ++rb) {
        float mm = pm[((size_t)b * 64 + rb) * DIMC + c];
        float ss = ps[((size_t)b * 64 + rb) * DIMC + c];
        if (mm > m) { s = s * __expf(m - mm) + ss; m = mm; } else s += ss * __expf(mm - m);
    }
    Mst[idx] = m;
    Sinv[idx] = 1.f / s;
}

// ---------------- context = sum_n softmax_n(k)[n,d] * v[n,e]; v computed on the fly ----------------
__global__ __launch_bounds__(256) void context_kernel(
    const float* __restrict__ h, const float* __restrict__ vw,
    const float* __restrict__ kbuf, const float* __restrict__ Mst,
    const float* __restrict__ Sinv, float* __restrict__ ctx) {
    int b = blockIdx.z, hd = blockIdx.y, rb = blockIdx.x;  // rb < 16 (512 rows each)
    int tid = threadIdx.x, tx = tid & 15, ty = tid >> 4;
    __shared__ float hs[32][68];
    __shared__ float wv[32][64];
    __shared__ float kx[64][64];
    __shared__ float vx[64][64];
    float cacc[4][4] = {};
    for (int sub = 0; sub < 8; ++sub) {
        size_t r0 = (size_t)b * NN + (size_t)rb * 512 + sub * 64;
        // v tile (64 rows x 64 head-cols), K=512
        float vacc[4][4] = {};
        for (int kk = 0; kk < DIMC; kk += 32) {
            #pragma unroll
            for (int i = 0; i < 2; ++i) {
                int idx = tid * 2 + i;
                int r = idx >> 3, c4 = (idx & 7) * 4;
                float4 v = *(const float4*)(h + (r0 + r) * DIMC + kk + c4);
                hs[c4 + 0][r] = v.x; hs[c4 + 1][r] = v.y;
                hs[c4 + 2][r] = v.z; hs[c4 + 3][r] = v.w;
            }
            #pragma unroll
            for (int i = 0; i < 2; ++i) {
                int idx = tid * 2 + i;
                int r = idx >> 4, c4 = (idx & 15) * 4;
                *(float4*)&wv[r][c4] = *(const float4*)(vw + (size_t)(kk + r) * DIMC + hd * 64 + c4);
            }
            __syncthreads();
            #pragma unroll
            for (int k2 = 0; k2 < 32; ++k2) {
                float4 a4 = *(const float4*)&hs[k2][ty * 4];
                float4 b4 = *(const float4*)&wv[k2][tx * 4];
                float av[4] = {a4.x, a4.y, a4.z, a4.w};
                float bv[4] = {b4.x, b4.y, b4.z, b4.w};
                #pragma unroll
                for (int i = 0; i < 4; ++i)
                    #pragma unroll
                    for (int j = 0; j < 4; ++j)
                        vacc[i][j] = fmaf(av[i], bv[j], vacc[i][j]);
            }
            __syncthreads();
        }
        #pragma unroll
        for (int i = 0; i < 4; ++i)
            *(float4*)&vx[ty * 4 + i][tx * 4] = make_float4(vacc[i][0], vacc[i][1], vacc[i][2], vacc[i][3]);
        // exp'd k tile
        #pragma unroll
        for (int i = 0; i < 4; ++i) {
            int idx = tid + 256 * i;
            int r = idx >> 4, c4 = (idx & 15) * 4;
            float4 v = *(const float4*)(kbuf + (r0 + r) * DIMC + hd * 64 + c4);
            int cb = b * DIMC + hd * 64 + c4;
            v.x = __expf(v.x - Mst[cb + 0]) * Sinv[cb + 0];
            v.y = __expf(v.y - Mst[cb + 1]) * Sinv[cb + 1];
            v.z = __expf(v.z - Mst[cb + 2]) * Sinv[cb + 2];
            v.w = __expf(v.w - Mst[cb + 3]) * Sinv[cb + 3];
            *(float4*)&kx[r][c4] = v;
        }
        __syncthreads();
        #pragma unroll
        for (int r = 0; r < 64; ++r) {
            float4 a4 = *(const float4*)&kx[r][ty * 4];
            float4 b4 = *(const float4*)&vx[r][tx * 4];
            float av[4] = {a4.x, a4.y, a4.z, a4.w};
            float bv[4] = {b4.x, b4.y, b4.z, b4.w};
            #pragma unroll
            for (int i = 0; i < 4; ++i)
                #pragma unroll
                for (int j = 0; j < 4; ++j)
                    cacc[i][j] = fmaf(av[i], bv[j], cacc[i][j]);
        }
        __syncthreads();
    }
    size_t cbase = (size_t)(b * HEADS + hd) * 64 * 64;
    #pragma unroll
    for (int i = 0; i < 4; ++i)
        #pragma unroll
        for (int j = 0; j < 4; ++j)
            atomicAdd(&ctx[cbase + (size_t)(ty * 4 + i) * 64 + tx * 4 + j], cacc[i][j]);
}

// ---------------- attn = (softmax_feat(h@q_w)/8) @ ctx ----------------
__global__ __launch_bounds__(256) void attn_kernel(
    const float* __restrict__ h, const float* __restrict__ qw,
    const float* __restrict__ ctx, float* __restrict__ attn) {
    int b = blockIdx.z, hd = blockIdx.y, rb = blockIdx.x;  // rb < 128 (64 rows each)
    int tid = threadIdx.x, tx = tid & 15, ty = tid >> 4;
    __shared__ float hs[32][68];
    __shared__ float wq[32][64];
    __shared__ float qs[64][65];
    __shared__ float cs[64][64];
    size_t r0 = (size_t)b * NN + (size_t)rb * 64;
    float qacc[4][4] = {};
    for (int kk = 0; kk < DIMC; kk += 32) {
        #pragma unroll
        for (int i = 0; i < 2; ++i) {
            int idx = tid * 2 + i;
            int r = idx >> 3, c4 = (idx & 7) * 4;
            float4 v = *(const float4*)(h + (r0 + r) * DIMC + kk + c4);
            hs[c4 + 0][r] = v.x; hs[c4 + 1][r] = v.y;
            hs[c4 + 2][r] = v.z; hs[c4 + 3][r] = v.w;
        }
        #pragma unroll
        for (int i = 0; i < 2; ++i) {
            int idx = tid * 2 + i;
            int r = idx >> 4, c4 = (idx & 15) * 4;
            *(float4*)&wq[r][c4] = *(const float4*)(qw + (size_t)(kk + r) * DIMC + hd * 64 + c4);
        }
        __syncthreads();
        #pragma unroll
        for (int k2 = 0; k2 < 32; ++k2) {
            float4 a4 = *(const float4*)&hs[k2][ty * 4];
            float4 b4 = *(const float4*)&wq[k2][tx * 4];
            float av[4] = {a4.x, a4.y, a4.z, a4.w};
            float bv[4] = {b4.x, b4.y, b4.z, b4.w};
            #pragma unroll
            for (int i = 0; i < 4; ++i)
                #pragma unroll
                for (int j = 0; j < 4; ++j)
                    qacc[i][j] = fmaf(av[i], bv[j], qacc[i][j]);
        }
        __syncthreads();
    }
    #pragma unroll
    for (int i = 0; i < 4; ++i)
        #pragma unroll
        for (int j = 0; j < 4; ++j)
            qs[ty * 4 + i][tx * 4 + j] = qacc[i][j];
    #pragma unroll
    for (int i = 0; i < 4; ++i) {
        int idx = tid + 256 * i;
        int r = idx >> 4, c4 = (idx & 15) * 4;
        *(float4*)&cs[r][c4] = *(const float4*)(ctx + ((size_t)(b * HEADS + hd) * 64 + r) * 64 + c4);
    }
    __syncthreads();
    if (tid < 64) {
        float m = -1e30f;
        #pragma unroll
        for (int d = 0; d < 64; ++d) m = fmaxf(m, qs[tid][d]);
        float s = 0.f;
        #pragma unroll
        for (int d = 0; d < 64; ++d) { float e = __expf(qs[tid][d] - m); qs[tid][d] = e; s += e; }
        float inv = 0.125f / s;  // * DH^-0.5
        #pragma unroll
        for (int d = 0; d < 64; ++d) qs[tid][d] *= inv;
    }
    __syncthreads();
    float aacc[4][4] = {};
    #pragma unroll
    for (int d = 0; d < 64; ++d) {
        float4 b4 = *(const float4*)&cs[d][tx * 4];
        float bv[4] = {b4.x, b4.y, b4.z, b4.w};
        #pragma unroll
        for (int i = 0; i < 4; ++i) {
            float a = qs[ty * 4 + i][d];
            #pragma unroll
            for (int j = 0; j < 4; ++j)
                aacc[i][j] = fmaf(a, bv[j], aacc[i][j]);
        }
    }
    #pragma unroll
    for (int i = 0; i < 4; ++i)
        *(float4*)&attn[(r0 + ty * 4 + i) * DIMC + hd * 64 + tx * 4] =
            make_float4(aacc[i][0], aacc[i][1], aacc[i][2], aacc[i][3]);
}

// ---------------- pos head: out[row, 0:2] = x[row]@w + b ----------------
__global__ __launch_bounds__(256) void pos_kernel(
    const float* __restrict__ x, const float* __restrict__ w,
    const float* __restrict__ b2, float* __restrict__ out) {
    int lane = threadIdx.x & 63;
    size_t row = (size_t)blockIdx.x * 4 + (threadIdx.x >> 6);
    const float* xp = x + row * DIMC;
    float acc0 = 0.f, acc1 = 0.f;
    #pragma unroll
    for (int i = 0; i < 2; ++i) {
        float4 xv = *(const float4*)(xp + lane * 8 + i * 4);
        const float* wp = w + (size_t)(lane * 8 + i * 4) * 2;
        float4 w0 = *(const float4*)(wp);
        float4 w1 = *(const float4*)(wp + 4);
        acc0 += xv.x * w0.x + xv.y * w0.z + xv.z * w1.x + xv.w * w1.z;
        acc1 += xv.x * w0.y + xv.y * w0.w + xv.z * w1.y + xv.w * w1.w;
    }
    #pragma unroll
    for (int o = 32; o; o >>= 1) { acc0 += __shfl_down(acc0, o, 64); acc1 += __shfl_down(acc1, o, 64); }
    if (lane == 0) {
        out[row * 2] = acc0 + b2[0];
        out[row * 2 + 1] = acc1 + b2[1];
    }
}

// ---------------- launch ----------------
extern "C" void kernel_launch(void* const* d_in, const int* in_sizes, int n_in,
                              void* d_out, int out_size, void* d_ws, size_t ws_size,
                              hipStream_t stream) {
    (void)in_sizes; (void)n_in; (void)out_size; (void)ws_size;
    const float* nf  = (const float*)d_in[0];
    const float* dt  = (const float*)d_in[1];
    const float* pos = (const float*)d_in[2];
    const float* msk = (const float*)d_in[3];
    const float* yyw = (const float*)d_in[4];
    const float* yyb = (const float*)d_in[5];
    const float* p1w = (const float*)d_in[6];
    const float* p1b = (const float*)d_in[7];
    const float* p2w = (const float*)d_in[8];
    const float* p2b = (const float*)d_in[9];
    const float* lxw = (const float*)d_in[10];
    const float* lxb = (const float*)d_in[11];
    const float* cw  = (const float*)d_in[12];
    const float* cb  = (const float*)d_in[13];
    const float* l1g = (const float*)d_in[14];
    const float* l1b = (const float*)d_in[15];
    const float* qw  = (const float*)d_in[16];
    const float* kw  = (const float*)d_in[17];
    const float* vw  = (const float*)d_in[18];
    const float* aow = (const float*)d_in[19];
    const float* aob = (const float*)d_in[20];
    const float* l2g = (const float*)d_in[21];
    const float* l2b = (const float*)d_in[22];
    const float* f1w = (const float*)d_in[23];
    const float* f1b = (const float*)d_in[24];
    const float* f2w = (const float*)d_in[25];
    const float* f2b = (const float*)d_in[26];
    const float* hpw = (const float*)d_in[27];
    const float* hpb = (const float*)d_in[28];

    float* ws    = (float*)d_ws;
    float* hbuf  = ws + OFF_H;
    float* kbuf  = ws + OFF_K;     // k -> attn -> ff mid
    float* dlt   = ws + OFF_DELTA;
    float* yv    = ws + OFF_Y;
    float* bb    = ws + OFF_BB;
    float* wcomp = ws + OFF_WCOMP;
    float* pm    = ws + OFF_PM;
    float* ps2   = ws + OFF_PS;
    float* Mst   = ws + OFF_M;
    float* Sinv  = ws + OFF_SINV;
    float* ctx   = ws + OFF_CTX;

    float* xout = (float*)d_out;                 // (4,8192,512) -- holds cat, then x
    float* yout = xout + (size_t)ROWS * DIMC;    // (4,128)
    float* pout = yout + NB * DT;                // (4,8192,2)

    // y + per-batch cat bias + composed weight
    y_kernel<<<4, 128, 0, stream>>>(dt, yyw, yyb, yv, yout);
    bb_kernel<<<8, 256, 0, stream>>>(lxb, cw, cb, yv, bb);
    {
        dim3 g(8, 8);
        gemm_f32<0><<<g, 256, 0, stream>>>(lxw, cw, nullptr, nullptr, wcomp,
                                           512, 512, 512, nullptr, nullptr, 0, 0);
    }
    delta_kernel<<<8192, 256, 0, stream>>>(pos, msk, p1w, p1b, p2w, p2b, dlt);

    // cat = nf@wcomp + delta@cw[512:576] + bb[batch]  -> xout
    {
        dim3 g(8, 512);
        gemm_f32<3><<<g, 256, 0, stream>>>(nf, wcomp, nullptr, bb, xout,
                                           ROWS, DIMC, DIMC, dlt, cw + (size_t)DIMC * DIMC, DELTA, NN);
    }
    ln_kernel<<<ROWS, 128, 0, stream>>>(xout, hbuf, l1g, l1b);

    // k projection, column-softmax stats
    {
        dim3 g(8, 512);
        gemm_f32<0><<<g, 256, 0, stream>>>(hbuf, kw, nullptr, nullptr, kbuf,
                                           ROWS, DIMC, DIMC, nullptr, nullptr, 0, 0);
    }
    {
        dim3 g(64, 4);
        ksm_stats1<<<g, 256, 0, stream>>>(kbuf, pm, ps2);
    }
    ksm_stats2<<<8, 256, 0, stream>>>(pm, ps2, Mst, Sinv);

    // context (v fused), then attn (q fused), then output proj + residual
    hipMemsetAsync(ctx, 0, (size_t)NB * HEADS * 64 * 64 * sizeof(float), stream);
    {
        dim3 g(16, HEADS, NB);
        context_kernel<<<g, 256, 0, stream>>>(hbuf, vw, kbuf, Mst, Sinv, ctx);
    }
    {
        dim3 g(128, HEADS, NB);
        attn_kernel<<<g, 256, 0, stream>>>(hbuf, qw, ctx, kbuf);
    }
    {
        dim3 g(8, 512);
        gemm_f32<2><<<g, 256, 0, stream>>>(kbuf, aow, aob, nullptr, xout,
                                           ROWS, DIMC, DIMC, nullptr, nullptr, 0, 0);
    }

    // FF block
    ln_kernel<<<ROWS, 128, 0, stream>>>(xout, hbuf, l2g, l2b);
    for (int b = 0; b < NB; ++b) {
        dim3 g1(32, 128);
        gemm_f32<1><<<g1, 256, 0, stream>>>(hbuf + (size_t)b * NN * DIMC, f1w, f1b, nullptr, kbuf,
                                            NN, FF, DIMC, nullptr, nullptr, 0, 0);
        dim3 g2(8, 128);
        gemm_f32<2><<<g2, 256, 0, stream>>>(kbuf, f2w, f2b, nullptr, xout + (size_t)b * NN * DIMC,
                                            NN, DIMC, FF, nullptr, nullptr, 0, 0);
    }

    pos_kernel<<<8192, 256, 0, stream>>>(xout, hpw, hpb, pout);
}

// Round 2
// 895.613 us; speedup vs baseline: 4.0625x; 4.0625x over previous
//
#include <hip/hip_runtime.h>
#include <hip/hip_bf16.h>
#include <math.h>

// ---------------- constants ----------------
#define NB 4
#define NN 8192
#define ROWS (NB*NN)          // 32768
#define DIMC 512
#define HEADS 8
#define DT 128
#define DELTA 64
#define FF 2048

// ---------------- workspace layout (float units) ----------------
// HB: bf16 h (LN1 out, later LN2 out)              8,388,608 f
// KB: region reused: nfb(bf16) -> kb(bf16) -> caw(f32)+cawT(bf16) -> mid(bf16)
// VB: dltb(bf16, front) -> vb(bf16)
// QB: lxwb+cw0T (bf16, front, consumed early) -> qb(bf16)
#define OFF_HB     ((size_t)0)
#define OFF_KB     ((size_t)8388608)
#define OFF_VB     ((size_t)16777216)
#define OFF_QB     ((size_t)25165824)
#define OFF_WCOMPT ((size_t)33554432)
#define OFF_CW2T   ((size_t)33685504)
#define OFF_KWT    ((size_t)33701888)
#define OFF_VWT    ((size_t)33832960)
#define OFF_QWT    ((size_t)33964032)
#define OFF_F1WT   ((size_t)34095104)
#define OFF_F2WT   ((size_t)34619392)
#define OFF_Y      ((size_t)35143680)
#define OFF_BBT    ((size_t)35144192)
#define OFF_PM     ((size_t)35146240)
#define OFF_PS     ((size_t)35277312)
#define OFF_M      ((size_t)35408384)
#define OFF_SINV   ((size_t)35410432)
#define OFF_CTX    ((size_t)35412480)
// end = 35,543,552 floats = 142.2 MB (round-1 used 147.9 MB -> known safe)

typedef __attribute__((ext_vector_type(8))) short bf16x8;
typedef __attribute__((ext_vector_type(4))) float f32x4;
typedef __attribute__((ext_vector_type(8))) unsigned short us8;

static __device__ __forceinline__ unsigned short f2b(float x) {
    __hip_bfloat16 h = __float2bfloat16(x);
    return __builtin_bit_cast(unsigned short, h);
}
static __device__ __forceinline__ float b2f(unsigned short u) {
    return __bfloat162float(__builtin_bit_cast(__hip_bfloat16, u));
}
static __device__ __forceinline__ float gelu_tanh(float x) {
    float t = tanhf(0.7978845608028654f * (x + 0.044715f * x * x * x));
    return 0.5f * x * (1.0f + t);
}

#define GLOAD16(g, l) __builtin_amdgcn_global_load_lds( \
    (const __attribute__((address_space(1))) void*)(g), \
    (__attribute__((address_space(3))) void*)(l), 16, 0, 0)

// ---------------- tiny prologue kernels ----------------
__global__ void y_kernel(const float* __restrict__ dt, const float* __restrict__ yyw,
                         const float* __restrict__ yyb, float* __restrict__ y_ws,
                         float* __restrict__ y_out) {
    int idx = blockIdx.x * 128 + threadIdx.x;   // 512
    int b = idx >> 7, j = idx & 127;
    float acc = yyb[j];
    for (int c = 0; c < DT; ++c) acc += dt[b * DT + c] * yyw[c * DT + j];
    y_ws[idx] = acc;
    y_out[idx] = acc;
}

__global__ void bb_kernel(const float* __restrict__ linxb, const float* __restrict__ catw,
                          const float* __restrict__ catb, const float* __restrict__ y,
                          float* __restrict__ bb) {
    int idx = blockIdx.x * 256 + threadIdx.x;   // 2048
    int b = idx >> 9, n = idx & 511;
    float acc = catb[n];
    for (int c = 0; c < DIMC; ++c) acc += linxb[c] * catw[(size_t)c * DIMC + n];
    const float* cw3 = catw + (size_t)(DIMC + DELTA) * DIMC;
    for (int j = 0; j < DT; ++j) acc += y[b * DT + j] * cw3[(size_t)j * DIMC + n];
    bb[idx] = acc;
}

__global__ __launch_bounds__(256) void delta_kernel(
    const float* __restrict__ pos, const float* __restrict__ mask,
    const float* __restrict__ w1, const float* __restrict__ b1,
    const float* __restrict__ w2, const float* __restrict__ b2,
    unsigned short* __restrict__ delta) {
    int lane = threadIdx.x & 63;
    size_t row = (size_t)blockIdx.x * 4 + (threadIdx.x >> 6);
    float mk = mask[row];
    float px = pos[row * 2] * mk, py = pos[row * 2 + 1] * mk;
    float nrm = sqrtf(px * px + py * py) + 1e-7f;
    float ux = px / nrm, uy = py / nrm;
    float t1 = fmaxf(ux * w1[lane] + uy * w1[64 + lane] + b1[lane], 0.0f);
    float acc = b2[lane];
    #pragma unroll
    for (int j = 0; j < 64; ++j) {
        float tv = __shfl(t1, j, 64);
        acc += tv * w2[j * 64 + lane];
    }
    delta[row * DELTA + lane] = f2b(acc);
}

// f32 -> bf16 flat convert, 8 elems/thread
__global__ void conv_bf16(const float* __restrict__ in, unsigned short* __restrict__ out, int n8) {
    int i = blockIdx.x * 256 + threadIdx.x;
    if (i >= n8) return;
    const float* p = in + (size_t)i * 8;
    us8 o;
    #pragma unroll
    for (int j = 0; j < 8; ++j) o[j] = f2b(p[j]);
    *(us8*)(out + (size_t)i * 8) = o;
}

// f32 [R][C] -> bf16 [C][R] tiled transpose-convert
__global__ __launch_bounds__(256) void transconv(const float* __restrict__ in,
                                                 unsigned short* __restrict__ out, int R, int C) {
    __shared__ float tile[32][33];
    int bx = blockIdx.x * 32;  // col offset
    int by = blockIdx.y * 32;  // row offset
    int tx = threadIdx.x & 31, ty = threadIdx.x >> 5;  // 32 x 8
    #pragma unroll
    for (int i = 0; i < 4; ++i) {
        int r = ty + i * 8;
        tile[r][tx] = in[(size_t)(by + r) * C + bx + tx];
    }
    __syncthreads();
    #pragma unroll
    for (int i = 0; i < 4; ++i) {
        int r = ty + i * 8;
        out[(size_t)(bx + r) * R + by + tx] = f2b(tile[tx][r]);
    }
}

// LayerNorm: f32 in -> bf16 out
__global__ __launch_bounds__(128) void ln_kernel(
    const float* __restrict__ src, unsigned short* __restrict__ dst,
    const float* __restrict__ g, const float* __restrict__ bta) {
    size_t row = blockIdx.x;
    int t = threadIdx.x;
    const float* s = src + row * DIMC;
    float4 x = *(const float4*)(s + t * 4);
    float sum = x.x + x.y + x.z + x.w;
    float sq = x.x * x.x + x.y * x.y + x.z * x.z + x.w * x.w;
    #pragma unroll
    for (int o = 32; o; o >>= 1) { sum += __shfl_down(sum, o, 64); sq += __shfl_down(sq, o, 64); }
    __shared__ float sh[4];
    if ((t & 63) == 0) { sh[(t >> 6) * 2] = sum; sh[(t >> 6) * 2 + 1] = sq; }
    __syncthreads();
    sum = sh[0] + sh[2]; sq = sh[1] + sh[3];
    float mean = sum * (1.0f / DIMC);
    float var = sq * (1.0f / DIMC) - mean * mean;
    float rstd = rsqrtf(fmaxf(var, 0.0f) + 1e-5f);
    float4 gv = *(const float4*)(g + t * 4);
    float4 bv = *(const float4*)(bta + t * 4);
    ushort4 ov;
    ov.x = f2b((x.x - mean) * rstd * gv.x + bv.x);
    ov.y = f2b((x.y - mean) * rstd * gv.y + bv.y);
    ov.z = f2b((x.z - mean) * rstd * gv.z + bv.z);
    ov.w = f2b((x.w - mean) * rstd * gv.w + bv.w);
    *(ushort4*)(dst + row * DIMC + t * 4) = ov;
}

// ---------------- MFMA GEMM ----------------
// C[M,N] = A[M,K](bf16) @ Bt[N,K](bf16, transposed weights)  (+ A2@B2t phase)
// EPI: 1 = bf16 gelu(acc+bias); 2 = f32 C += acc + bias (in-place residual);
//      3 = f32 acc + extra[(row/batch_rows)*N+col]; 4 = bf16 acc; 5 = bf16 transposed store
#define BM 128
#define BN 128
#define BK 64

template <int EPI>
__global__ __launch_bounds__(256) void gemm_mfma(
    const unsigned short* __restrict__ A, int lda,
    const unsigned short* __restrict__ Bt,
    const unsigned short* __restrict__ A2, int lda2,
    const unsigned short* __restrict__ B2t, int K2,
    const float* __restrict__ bias,
    const float* __restrict__ extra, int batch_rows,
    void* __restrict__ Cv, int M, int N, int K,
    size_t b_stride, int rows_per_batch) {
    __shared__ unsigned short As[BM * BK];
    __shared__ unsigned short Bs[BN * BK];
    int bm = blockIdx.y * BM, bn = blockIdx.x * BN;
    int tid = threadIdx.x;
    int lane = tid & 63, wv = tid >> 6;
    int wr = (wv >> 1) * 64, wc = (wv & 1) * 64;
    int g16 = (lane >> 4) << 4;       // 0,16,32,48 (bytes)
    int lr = lane & 15;
    int sw = (lr & 7) << 4;           // lane-constant row swizzle

    const unsigned short* Bb = Bt;
    if (rows_per_batch) Bb = Bt + (size_t)(bm / rows_per_batch) * b_stride;

    f32x4 acc[4][4] = {};
    const char* Ab = (const char*)As;
    const char* Bp8 = (const char*)Bs;

    for (int ph = 0; ph < 2; ++ph) {
        const unsigned short* Ap = ph ? A2 : A;
        const unsigned short* Wp = ph ? B2t : Bb;
        int ldap = ph ? lda2 : lda;
        int Kp = ph ? K2 : K;
        if (Ap == nullptr || Kp == 0) continue;
        for (int k0 = 0; k0 < Kp; k0 += BK) {
            // stage A,B tiles: linear LDS dest, pre-swizzled global source
            #pragma unroll
            for (int i = 0; i < 4; ++i) {
                int idx = tid + 256 * i;
                int row = idx >> 3;
                int kb = (idx & 7) * 16;
                const char* g = (const char*)(Ap + (size_t)(bm + row) * ldap + k0)
                                + (kb ^ ((row & 7) << 4));
                GLOAD16(g, (char*)As + idx * 16);
            }
            #pragma unroll
            for (int i = 0; i < 4; ++i) {
                int idx = tid + 256 * i;
                int row = idx >> 3;
                int kb = (idx & 7) * 16;
                const char* g = (const char*)(Wp + (size_t)(bn + row) * Kp + k0)
                                + (kb ^ ((row & 7) << 4));
                GLOAD16(g, (char*)Bs + idx * 16);
            }
            __syncthreads();
            #pragma unroll
            for (int s = 0; s < 2; ++s) {
                int koff = s * 64 + g16;
                bf16x8 af[4], bw[4];
                #pragma unroll
                for (int f = 0; f < 4; ++f) {
                    int ar = wr + f * 16 + lr;
                    af[f] = *(const bf16x8*)(Ab + ar * 128 + (koff ^ sw));
                    int br = wc + f * 16 + lr;
                    bw[f] = *(const bf16x8*)(Bp8 + br * 128 + (koff ^ sw));
                }
                #pragma unroll
                for (int f = 0; f < 4; ++f)
                    #pragma unroll
                    for (int j = 0; j < 4; ++j)
                        acc[f][j] = __builtin_amdgcn_mfma_f32_16x16x32_bf16(
                            af[f], bw[j], acc[f][j], 0, 0, 0);
            }
            __syncthreads();
        }
    }

    int g4 = (lane >> 4) * 4;
    #pragma unroll
    for (int f = 0; f < 4; ++f) {
        #pragma unroll
        for (int j = 0; j < 4; ++j) {
            int col = bn + wc + j * 16 + lr;
            #pragma unroll
            for (int r = 0; r < 4; ++r) {
                int rr = bm + wr + f * 16 + g4 + r;
                size_t idx = (size_t)rr * N + col;
                float v = acc[f][j][r];
                if (EPI == 1) {
                    ((unsigned short*)Cv)[idx] = f2b(gelu_tanh(v + bias[col]));
                } else if (EPI == 2) {
                    ((float*)Cv)[idx] += v + bias[col];
                } else if (EPI == 3) {
                    ((float*)Cv)[idx] = v + extra[(size_t)(rr / batch_rows) * N + col];
                } else if (EPI == 4) {
                    ((unsigned short*)Cv)[idx] = f2b(v);
                } else if (EPI == 5) {
                    ((unsigned short*)Cv)[(size_t)col * M + rr] = f2b(v);
                }
            }
        }
    }
}

// ---------------- k column-softmax stats (softmax over sequence dim) ----------------
__global__ __launch_bounds__(256) void ksm_stats1(
    const unsigned short* __restrict__ k, float* __restrict__ pm, float* __restrict__ ps) {
    int b = blockIdx.y, rb = blockIdx.x;
    const unsigned short* kp = k + ((size_t)b * NN + (size_t)rb * 128) * DIMC;
    int t = threadIdx.x;
    float m0 = -1e30f, s0 = 0.f, m1 = -1e30f, s1 = 0.f;
    for (int r = 0; r < 128; ++r) {
        float x0 = b2f(kp[(size_t)r * DIMC + t]);
        float x1 = b2f(kp[(size_t)r * DIMC + t + 256]);
        if (x0 > m0) { s0 = s0 * __expf(m0 - x0) + 1.f; m0 = x0; } else s0 += __expf(x0 - m0);
        if (x1 > m1) { s1 = s1 * __expf(m1 - x1) + 1.f; m1 = x1; } else s1 += __expf(x1 - m1);
    }
    size_t base = ((size_t)b * 64 + rb) * DIMC;
    pm[base + t] = m0; pm[base + t + 256] = m1;
    ps[base + t] = s0; ps[base + t + 256] = s1;
}

__global__ void ksm_stats2(const float* __restrict__ pm, const float* __restrict__ ps,
                           float* __restrict__ Mst, float* __restrict__ Sinv) {
    int idx = blockIdx.x * 256 + threadIdx.x;
    int b = idx >> 9, c = idx & 511;
    float m = -1e30f, s = 0.f;
    for (int rb = 0; rb < 64; ++rb) {
        float mm = pm[((size_t)b * 64 + rb) * DIMC + c];
        float ss = ps[((size_t)b * 64 + rb) * DIMC + c];
        if (mm > m) { s = s * __expf(m - mm) + ss; m = mm; } else s += ss * __expf(mm - m);
    }
    Mst[idx] = m;
    Sinv[idx] = 1.f / s;
}

// ---------------- context = sum_n expk[n,d] * v[n,e] ----------------
__global__ __launch_bounds__(256) void context_kernel(
    const unsigned short* __restrict__ kb, const unsigned short* __restrict__ vb,
    const float* __restrict__ Mst, const float* __restrict__ Sinv,
    float* __restrict__ ctx) {
    int b = blockIdx.z, hd = blockIdx.y, rb = blockIdx.x;  // rb < 16 (512 rows each)
    int tid = threadIdx.x, tx = tid & 15, ty = tid >> 4;
    __shared__ float kx[64][68];
    __shared__ float vx[64][68];
    int r0t = tid >> 3;            // 0..31
    int c8 = (tid & 7) * 8;
    int cb = hd * 64 + c8;
    float mv[8], sv[8];
    #pragma unroll
    for (int j = 0; j < 8; ++j) { mv[j] = Mst[b * DIMC + cb + j]; sv[j] = Sinv[b * DIMC + cb + j]; }
    float cacc[4][4] = {};
    for (int sub = 0; sub < 8; ++sub) {
        size_t row0 = (size_t)b * NN + (size_t)rb * 512 + sub * 64;
        #pragma unroll
        for (int i = 0; i < 2; ++i) {
            int r = r0t + i * 32;
            us8 kv = *(const us8*)(kb + (row0 + r) * DIMC + cb);
            us8 vv = *(const us8*)(vb + (row0 + r) * DIMC + cb);
            #pragma unroll
            for (int j = 0; j < 8; ++j) {
                kx[r][c8 + j] = __expf(b2f(kv[j]) - mv[j]) * sv[j];
                vx[r][c8 + j] = b2f(vv[j]);
            }
        }
        __syncthreads();
        #pragma unroll 4
        for (int r = 0; r < 64; ++r) {
            float4 a4 = *(const float4*)&kx[r][ty * 4];
            float4 b4 = *(const float4*)&vx[r][tx * 4];
            float av[4] = {a4.x, a4.y, a4.z, a4.w};
            float bv[4] = {b4.x, b4.y, b4.z, b4.w};
            #pragma unroll
            for (int i = 0; i < 4; ++i)
                #pragma unroll
                for (int j = 0; j < 4; ++j)
                    cacc[i][j] = fmaf(av[i], bv[j], cacc[i][j]);
        }
        __syncthreads();
    }
    size_t cbase = (size_t)(b * HEADS + hd) * 64 * 64;
    #pragma unroll
    for (int i = 0; i < 4; ++i)
        #pragma unroll
        for (int j = 0; j < 4; ++j)
            atomicAdd(&ctx[cbase + (size_t)(ty * 4 + i) * 64 + tx * 4 + j], cacc[i][j]);
}

// ---------------- q feature-softmax in place (bf16) ----------------
__global__ __launch_bounds__(256) void qsm_kernel(unsigned short* __restrict__ qb) {
    int lane = threadIdx.x & 63;
    size_t row = (size_t)blockIdx.x * 4 + (threadIdx.x >> 6);
    size_t base = row * DIMC;
    #pragma unroll
    for (int h = 0; h < 8; ++h) {
        float v = b2f(qb[base + h * 64 + lane]);
        float m = v;
        #pragma unroll
        for (int o = 32; o; o >>= 1) m = fmaxf(m, __shfl_xor(m, o, 64));
        float e = __expf(v - m);
        float s = e;
        #pragma unroll
        for (int o = 32; o; o >>= 1) s += __shfl_xor(s, o, 64);
        qb[base + h * 64 + lane] = f2b(e * (0.125f / s));
    }
}

// ---------------- caw[b][h*64+d][n] = sum_e ctx[b][h][d][e] * aow[h*64+e][n] ----------------
__global__ __launch_bounds__(256) void caw_kernel(const float* __restrict__ ctx,
                                                  const float* __restrict__ aow,
                                                  float* __restrict__ caw) {
    int nt = blockIdx.x, hd = blockIdx.y, b = blockIdx.z;
    int tid = threadIdx.x, tx = tid & 15, ty = tid >> 4;
    __shared__ float cs[64][68];
    __shared__ float aw[64][68];
    #pragma unroll
    for (int i = 0; i < 4; ++i) {
        int idx = tid + 256 * i;
        int r = idx >> 4, c4 = (idx & 15) * 4;
        *(float4*)&cs[r][c4] = *(const float4*)(ctx + ((size_t)(b * HEADS + hd) * 64 + r) * 64 + c4);
        *(float4*)&aw[r][c4] = *(const float4*)(aow + (size_t)(hd * 64 + r) * DIMC + nt * 64 + c4);
    }
    __syncthreads();
    float acc[4][4] = {};
    for (int e = 0; e < 64; ++e) {
        float av[4];
        #pragma unroll
        for (int i = 0; i < 4; ++i) av[i] = cs[ty * 4 + i][e];
        float4 b4 = *(const float4*)&aw[e][tx * 4];
        float bv[4] = {b4.x, b4.y, b4.z, b4.w};
        #pragma unroll
        for (int i = 0; i < 4; ++i)
            #pragma unroll
            for (int j = 0; j < 4; ++j)
                acc[i][j] = fmaf(av[i], bv[j], acc[i][j]);
    }
    #pragma unroll
    for (int i = 0; i < 4; ++i)
        #pragma unroll
        for (int j = 0; j < 4; ++j)
            caw[(size_t)b * DIMC * DIMC + (size_t)(hd * 64 + ty * 4 + i) * DIMC + nt * 64 + tx * 4 + j]
                = acc[i][j];
}

// ---------------- pos head ----------------
__global__ __launch_bounds__(256) void pos_kernel(
    const float* __restrict__ x, const float* __restrict__ w,
    const float* __restrict__ b2, float* __restrict__ out) {
    int lane = threadIdx.x & 63;
    size_t row = (size_t)blockIdx.x * 4 + (threadIdx.x >> 6);
    const float* xp = x + row * DIMC;
    float acc0 = 0.f, acc1 = 0.f;
    #pragma unroll
    for (int i = 0; i < 2; ++i) {
        float4 xv = *(const float4*)(xp + lane * 8 + i * 4);
        const float* wp = w + (size_t)(lane * 8 + i * 4) * 2;
        float4 w0 = *(const float4*)(wp);
        float4 w1 = *(const float4*)(wp + 4);
        acc0 += xv.x * w0.x + xv.y * w0.z + xv.z * w1.x + xv.w * w1.z;
        acc1 += xv.x * w0.y + xv.y * w0.w + xv.z * w1.y + xv.w * w1.w;
    }
    #pragma unroll
    for (int o = 32; o; o >>= 1) { acc0 += __shfl_down(acc0, o, 64); acc1 += __shfl_down(acc1, o, 64); }
    if (lane == 0) {
        out[row * 2] = acc0 + b2[0];
        out[row * 2 + 1] = acc1 + b2[1];
    }
}

// ---------------- launch ----------------
extern "C" void kernel_launch(void* const* d_in, const int* in_sizes, int n_in,
                              void* d_out, int out_size, void* d_ws, size_t ws_size,
                              hipStream_t stream) {
    (void)in_sizes; (void)n_in; (void)out_size; (void)ws_size;
    const float* nf  = (const float*)d_in[0];
    const float* dt  = (const float*)d_in[1];
    const float* pos = (const float*)d_in[2];
    const float* msk = (const float*)d_in[3];
    const float* yyw = (const float*)d_in[4];
    const float* yyb = (const float*)d_in[5];
    const float* p1w = (const float*)d_in[6];
    const float* p1b = (const float*)d_in[7];
    const float* p2w = (const float*)d_in[8];
    const float* p2b = (const float*)d_in[9];
    const float* lxw = (const float*)d_in[10];
    const float* lxb = (const float*)d_in[11];
    const float* cw  = (const float*)d_in[12];
    const float* cb  = (const float*)d_in[13];
    const float* l1g = (const float*)d_in[14];
    const float* l1b = (const float*)d_in[15];
    const float* qw  = (const float*)d_in[16];
    const float* kw  = (const float*)d_in[17];
    const float* vw  = (const float*)d_in[18];
    const float* aow = (const float*)d_in[19];
    const float* aob = (const float*)d_in[20];
    const float* l2g = (const float*)d_in[21];
    const float* l2b = (const float*)d_in[22];
    const float* f1w = (const float*)d_in[23];
    const float* f1b = (const float*)d_in[24];
    const float* f2w = (const float*)d_in[25];
    const float* f2b_ = (const float*)d_in[26];
    const float* hpw = (const float*)d_in[27];
    const float* hpb = (const float*)d_in[28];

    float* ws = (float*)d_ws;
    unsigned short* hb_u     = (unsigned short*)(ws + OFF_HB);
    unsigned short* nfb_u    = (unsigned short*)(ws + OFF_KB);
    unsigned short* kb_u     = (unsigned short*)(ws + OFF_KB);
    float*          caw      = ws + OFF_KB;
    unsigned short* cawT_u   = (unsigned short*)(ws + OFF_KB + 1048576);
    unsigned short* mid_u    = (unsigned short*)(ws + OFF_KB);
    unsigned short* dltb_u   = (unsigned short*)(ws + OFF_VB);
    unsigned short* vb_u     = (unsigned short*)(ws + OFF_VB);
    unsigned short* lxwb_u   = (unsigned short*)(ws + OFF_QB);
    unsigned short* cw0T_u   = (unsigned short*)(ws + OFF_QB + 131072);
    unsigned short* qb_u     = (unsigned short*)(ws + OFF_QB);
    unsigned short* wcompT_u = (unsigned short*)(ws + OFF_WCOMPT);
    unsigned short* cw2T_u   = (unsigned short*)(ws + OFF_CW2T);
    unsigned short* kwT_u    = (unsigned short*)(ws + OFF_KWT);
    unsigned short* vwT_u    = (unsigned short*)(ws + OFF_VWT);
    unsigned short* qwT_u    = (unsigned short*)(ws + OFF_QWT);
    unsigned short* f1wT_u   = (unsigned short*)(ws + OFF_F1WT);
    unsigned short* f2wT_u   = (unsigned short*)(ws + OFF_F2WT);
    float* yv   = ws + OFF_Y;
    float* bbf  = ws + OFF_BBT;
    float* pm   = ws + OFF_PM;
    float* ps2  = ws + OFF_PS;
    float* Mst  = ws + OFF_M;
    float* Sinv = ws + OFF_SINV;
    float* ctx  = ws + OFF_CTX;

    float* xout = (float*)d_out;
    float* yout = xout + (size_t)ROWS * DIMC;
    float* pout = yout + NB * DT;

    // prologue scalars + weight conversions
    y_kernel<<<4, 128, 0, stream>>>(dt, yyw, yyb, yv, yout);
    bb_kernel<<<8, 256, 0, stream>>>(lxb, cw, cb, yv, bbf);
    conv_bf16<<<128, 256, 0, stream>>>(lxw, lxwb_u, 32768);
    transconv<<<dim3(16, 16), 256, 0, stream>>>(cw, cw0T_u, 512, 512);
    transconv<<<dim3(16, 2), 256, 0, stream>>>(cw + (size_t)DIMC * DIMC, cw2T_u, 64, 512);
    transconv<<<dim3(16, 16), 256, 0, stream>>>(kw, kwT_u, 512, 512);
    transconv<<<dim3(16, 16), 256, 0, stream>>>(vw, vwT_u, 512, 512);
    transconv<<<dim3(16, 16), 256, 0, stream>>>(qw, qwT_u, 512, 512);
    transconv<<<dim3(64, 16), 256, 0, stream>>>(f1w, f1wT_u, 512, 2048);
    transconv<<<dim3(16, 64), 256, 0, stream>>>(f2w, f2wT_u, 2048, 512);
    conv_bf16<<<8192, 256, 0, stream>>>(nf, nfb_u, 2097152);
    delta_kernel<<<8192, 256, 0, stream>>>(pos, msk, p1w, p1b, p2w, p2b, dltb_u);

    // wcompT = (lxw @ cw0)^T in bf16
    gemm_mfma<5><<<dim3(4, 4), 256, 0, stream>>>(
        lxwb_u, 512, cw0T_u, nullptr, 0, nullptr, 0,
        nullptr, nullptr, 0, wcompT_u, 512, 512, 512, 0, 0);

    // cat = nf@wcomp + delta@cw2 + bb[batch] -> xout (f32)
    gemm_mfma<3><<<dim3(4, 256), 256, 0, stream>>>(
        nfb_u, 512, wcompT_u, dltb_u, 64, cw2T_u, 64,
        nullptr, bbf, NN, xout, ROWS, 512, 512, 0, 0);

    ln_kernel<<<ROWS, 128, 0, stream>>>(xout, hb_u, l1g, l1b);

    // k, v, q projections (bf16 out)
    gemm_mfma<4><<<dim3(4, 256), 256, 0, stream>>>(
        hb_u, 512, kwT_u, nullptr, 0, nullptr, 0,
        nullptr, nullptr, 0, kb_u, ROWS, 512, 512, 0, 0);
    gemm_mfma<4><<<dim3(4, 256), 256, 0, stream>>>(
        hb_u, 512, vwT_u, nullptr, 0, nullptr, 0,
        nullptr, nullptr, 0, vb_u, ROWS, 512, 512, 0, 0);
    gemm_mfma<4><<<dim3(4, 256), 256, 0, stream>>>(
        hb_u, 512, qwT_u, nullptr, 0, nullptr, 0,
        nullptr, nullptr, 0, qb_u, ROWS, 512, 512, 0, 0);

    // k sequence-softmax stats
    ksm_stats1<<<dim3(64, 4), 256, 0, stream>>>(kb_u, pm, ps2);
    ksm_stats2<<<8, 256, 0, stream>>>(pm, ps2, Mst, Sinv);

    // context
    hipMemsetAsync(ctx, 0, (size_t)NB * HEADS * 64 * 64 * sizeof(float), stream);
    context_kernel<<<dim3(16, HEADS, NB), 256, 0, stream>>>(kb_u, vb_u, Mst, Sinv, ctx);

    // q softmax in place; compose ctx with attn_out_w per batch
    qsm_kernel<<<8192, 256, 0, stream>>>(qb_u);
    caw_kernel<<<dim3(8, 8, 4), 256, 0, stream>>>(ctx, aow, caw);
    for (int b = 0; b < NB; ++b)
        transconv<<<dim3(16, 16), 256, 0, stream>>>(caw + (size_t)b * 262144,
                                                    cawT_u + (size_t)b * 262144, 512, 512);

    // x += qsm @ caw[b] + aob  (per-batch B)
    gemm_mfma<2><<<dim3(4, 256), 256, 0, stream>>>(
        qb_u, 512, cawT_u, nullptr, 0, nullptr, 0,
        aob, nullptr, 0, xout, ROWS, 512, 512, 262144, NN);

    // FF block
    ln_kernel<<<ROWS, 128, 0, stream>>>(xout, hb_u, l2g, l2b);
    for (int b = 0; b < NB; ++b) {
        gemm_mfma<1><<<dim3(16, 64), 256, 0, stream>>>(
            hb_u + (size_t)b * NN * DIMC, 512, f1wT_u, nullptr, 0, nullptr, 0,
            f1b, nullptr, 0, mid_u, NN, FF, 512, 0, 0);
        gemm_mfma<2><<<dim3(4, 64), 256, 0, stream>>>(
            mid_u, 2048, f2wT_u, nullptr, 0, nullptr, 0,
            f2b_, nullptr, 0, xout + (size_t)b * NN * DIMC, NN, 512, 2048, 0, 0);
    }

    pos_kernel<<<8192, 256, 0, stream>>>(xout, hpw, hpb, pout);
}

// Round 4
// 881.684 us; speedup vs baseline: 4.1267x; 1.0158x over previous
//
#include <hip/hip_runtime.h>
#include <hip/hip_bf16.h>
#include <math.h>

// ---------------- constants ----------------
#define NB 4
#define NN 8192
#define ROWS (NB*NN)          // 32768
#define DIMC 512
#define HEADS 8
#define DT 128
#define DELTA 64
#define FF 2048
#define KCAT 576

// ---------------- workspace layout (FLOAT units; bf16 buf of E elems = E/2 floats) ----------------
// R0 [9,437,184 f]: catA (32768x576 bf16 = 9,437,184 f) -> hb (32768x512 bf16 = 8,388,608 f)
//                   + caw (f32 4x512x512 = 1,048,576 f) at R0+8,388,608 (slack past hb)
// R1 [8,388,608 f]: kb (bf16) -> qb (bf16, after context) -> mid (8192x2048 bf16)
// R2 [8,388,608 f]: vb (bf16) -> cawT (bf16 4x512x512 = 524,288 f, after context)
#define OFF_R0     ((size_t)0)
#define OFF_CAW    ((size_t)8388608)
#define OFF_R1     ((size_t)9437184)
#define OFF_R2     ((size_t)17825792)
#define OFF_CATWT  ((size_t)26214400)   // bf16 [512][576] = 147,456 f
#define OFF_KWT    ((size_t)26361856)   // bf16 [512][512] = 131,072 f
#define OFF_VWT    ((size_t)26492928)
#define OFF_QWT    ((size_t)26624000)
#define OFF_F1WT   ((size_t)26755072)   // bf16 [2048][512] = 524,288 f
#define OFF_F2WT   ((size_t)27279360)   // bf16 [512][2048] = 524,288 f
#define OFF_LXWB   ((size_t)27803648)   // bf16 [512][512]
#define OFF_CW0T   ((size_t)27934720)   // bf16 [512][512]
#define OFF_Y      ((size_t)28065792)
#define OFF_BB     ((size_t)28066304)
#define OFF_PM     ((size_t)28068352)
#define OFF_PS     ((size_t)28199424)
#define OFF_M      ((size_t)28330496)
#define OFF_SINV   ((size_t)28332544)
#define OFF_CTX    ((size_t)28334592)
// end = 28,465,664 floats = 113.9 MB

typedef __attribute__((ext_vector_type(8))) short bf16x8;
typedef __attribute__((ext_vector_type(4))) float f32x4;
typedef __attribute__((ext_vector_type(8))) unsigned short us8;

static __device__ __forceinline__ unsigned short f2b(float x) {
    __hip_bfloat16 h = __float2bfloat16(x);
    return __builtin_bit_cast(unsigned short, h);
}
static __device__ __forceinline__ float b2f(unsigned short u) {
    return __bfloat162float(__builtin_bit_cast(__hip_bfloat16, u));
}
static __device__ __forceinline__ float gelu_tanh(float x) {
    float t = tanhf(0.7978845608028654f * (x + 0.044715f * x * x * x));
    return 0.5f * x * (1.0f + t);
}

#define GLOAD16(g, l) __builtin_amdgcn_global_load_lds( \
    (const __attribute__((address_space(1))) void*)(g), \
    (__attribute__((address_space(3))) void*)(l), 16, 0, 0)

// ---------------- tiny prologue kernels ----------------
__global__ void y_kernel(const float* __restrict__ dt, const float* __restrict__ yyw,
                         const float* __restrict__ yyb, float* __restrict__ y_ws,
                         float* __restrict__ y_out) {
    int idx = blockIdx.x * 128 + threadIdx.x;   // 512
    int b = idx >> 7, j = idx & 127;
    float acc = yyb[j];
    for (int c = 0; c < DT; ++c) acc += dt[b * DT + c] * yyw[c * DT + j];
    y_ws[idx] = acc;
    y_out[idx] = acc;
}

__global__ void bb_kernel(const float* __restrict__ linxb, const float* __restrict__ catw,
                          const float* __restrict__ catb, const float* __restrict__ y,
                          float* __restrict__ bb) {
    int idx = blockIdx.x * 256 + threadIdx.x;   // 2048
    int b = idx >> 9, n = idx & 511;
    float acc = catb[n];
    for (int c = 0; c < DIMC; ++c) acc += linxb[c] * catw[(size_t)c * DIMC + n];
    const float* cw3 = catw + (size_t)(DIMC + DELTA) * DIMC;
    for (int j = 0; j < DT; ++j) acc += y[b * DT + j] * cw3[(size_t)j * DIMC + n];
    bb[idx] = acc;
}

// delta -> catA columns 512..575 (row stride KCAT)
__global__ __launch_bounds__(256) void delta_kernel(
    const float* __restrict__ pos, const float* __restrict__ mask,
    const float* __restrict__ w1, const float* __restrict__ b1,
    const float* __restrict__ w2, const float* __restrict__ b2,
    unsigned short* __restrict__ catA) {
    int lane = threadIdx.x & 63;
    size_t row = (size_t)blockIdx.x * 4 + (threadIdx.x >> 6);
    float mk = mask[row];
    float px = pos[row * 2] * mk, py = pos[row * 2 + 1] * mk;
    float nrm = sqrtf(px * px + py * py) + 1e-7f;
    float ux = px / nrm, uy = py / nrm;
    float t1 = fmaxf(ux * w1[lane] + uy * w1[64 + lane] + b1[lane], 0.0f);
    float acc = b2[lane];
    #pragma unroll
    for (int j = 0; j < 64; ++j) {
        float tv = __shfl(t1, j, 64);
        acc += tv * w2[j * 64 + lane];
    }
    catA[row * KCAT + DIMC + lane] = f2b(acc);
}

// f32 -> bf16 flat convert, 8 elems/thread
__global__ void conv_bf16(const float* __restrict__ in, unsigned short* __restrict__ out, int n8) {
    int i = blockIdx.x * 256 + threadIdx.x;
    if (i >= n8) return;
    const float* p = in + (size_t)i * 8;
    us8 o;
    #pragma unroll
    for (int j = 0; j < 8; ++j) o[j] = f2b(p[j]);
    *(us8*)(out + (size_t)i * 8) = o;
}

// f32 [rows][512] -> bf16 out[row*ldo + c], 8 elems/thread
__global__ void conv_bf16_strided(const float* __restrict__ in, unsigned short* __restrict__ out,
                                  int ldo) {
    int i = blockIdx.x * 256 + threadIdx.x;   // total ROWS*64
    int row = i >> 6, c8 = (i & 63) * 8;
    const float* p = in + (size_t)row * DIMC + c8;
    us8 o;
    #pragma unroll
    for (int j = 0; j < 8; ++j) o[j] = f2b(p[j]);
    *(us8*)(out + (size_t)row * ldo + c8) = o;
}

// f32 [R][C] -> bf16 out[c*ldo + r] tiled transpose-convert
__global__ __launch_bounds__(256) void transconv(const float* __restrict__ in,
                                                 unsigned short* __restrict__ out,
                                                 int R, int C, int ldo) {
    __shared__ float tile[32][33];
    int bx = blockIdx.x * 32;  // col offset (input)
    int by = blockIdx.y * 32;  // row offset (input)
    int tx = threadIdx.x & 31, ty = threadIdx.x >> 5;  // 32 x 8
    #pragma unroll
    for (int i = 0; i < 4; ++i) {
        int r = ty + i * 8;
        tile[r][tx] = in[(size_t)(by + r) * C + bx + tx];
    }
    __syncthreads();
    #pragma unroll
    for (int i = 0; i < 4; ++i) {
        int r = ty + i * 8;
        out[(size_t)(bx + r) * ldo + by + tx] = f2b(tile[tx][r]);
    }
}

// LayerNorm: f32 in -> bf16 out
__global__ __launch_bounds__(128) void ln_kernel(
    const float* __restrict__ src, unsigned short* __restrict__ dst,
    const float* __restrict__ g, const float* __restrict__ bta) {
    size_t row = blockIdx.x;
    int t = threadIdx.x;
    const float* s = src + row * DIMC;
    float4 x = *(const float4*)(s + t * 4);
    float sum = x.x + x.y + x.z + x.w;
    float sq = x.x * x.x + x.y * x.y + x.z * x.z + x.w * x.w;
    #pragma unroll
    for (int o = 32; o; o >>= 1) { sum += __shfl_down(sum, o, 64); sq += __shfl_down(sq, o, 64); }
    __shared__ float sh[4];
    if ((t & 63) == 0) { sh[(t >> 6) * 2] = sum; sh[(t >> 6) * 2 + 1] = sq; }
    __syncthreads();
    sum = sh[0] + sh[2]; sq = sh[1] + sh[3];
    float mean = sum * (1.0f / DIMC);
    float var = sq * (1.0f / DIMC) - mean * mean;
    float rstd = rsqrtf(fmaxf(var, 0.0f) + 1e-5f);
    float4 gv = *(const float4*)(g + t * 4);
    float4 bv = *(const float4*)(bta + t * 4);
    ushort4 ov;
    ov.x = f2b((x.x - mean) * rstd * gv.x + bv.x);
    ov.y = f2b((x.y - mean) * rstd * gv.y + bv.y);
    ov.z = f2b((x.z - mean) * rstd * gv.z + bv.z);
    ov.w = f2b((x.w - mean) * rstd * gv.w + bv.w);
    *(ushort4*)(dst + row * DIMC + t * 4) = ov;
}

// ---------------- MFMA GEMM, 2-phase double-buffered ----------------
// C[M,N] = A[M,K](bf16, lda) @ Bt[N,K](bf16, ldb)
// EPI: 1 = bf16 gelu(acc+bias); 2 = f32 C += acc + bias;
//      3 = f32 acc + extra[(row/batch_rows)*N+col]; 4 = bf16 acc; 5 = bf16 C^T (ldo)
#define BM 128
#define BN 128
#define BK 64

template <int EPI>
__global__ __launch_bounds__(256) void gemm_mfma(
    const unsigned short* __restrict__ A, int lda,
    const unsigned short* __restrict__ Bt, int ldb,
    const float* __restrict__ bias,
    const float* __restrict__ extra, int batch_rows,
    void* __restrict__ Cv, int M, int N, int K,
    size_t b_stride, int rows_per_batch, int ldo) {
    __shared__ unsigned short As[2][BM * BK];
    __shared__ unsigned short Bs[2][BN * BK];
    int bm = blockIdx.y * BM, bn = blockIdx.x * BN;
    int tid = threadIdx.x;
    int lane = tid & 63, wv = tid >> 6;
    int wr = (wv >> 1) * 64, wc = (wv & 1) * 64;
    int g16 = (lane >> 4) << 4;       // 0,16,32,48 (bytes)
    int lr = lane & 15;
    int sw = (lr & 7) << 4;           // lane-constant row swizzle

    const unsigned short* Bb = Bt;
    if (rows_per_batch) Bb = Bt + (size_t)(bm / rows_per_batch) * b_stride;

    int srow = tid >> 3;              // +32 per i
    int skb = (tid & 7) * 16;
    int sxor = skb ^ ((srow & 7) << 4);

    auto stage = [&](int buf, int k0) {
        #pragma unroll
        for (int i = 0; i < 4; ++i) {
            int row = srow + 32 * i;
            const char* g = (const char*)(A + (size_t)(bm + row) * lda + k0) + sxor;
            GLOAD16(g, (char*)As[buf] + (size_t)(tid + 256 * i) * 16);
        }
        #pragma unroll
        for (int i = 0; i < 4; ++i) {
            int row = srow + 32 * i;
            const char* g = (const char*)(Bb + (size_t)(bn + row) * ldb + k0) + sxor;
            GLOAD16(g, (char*)Bs[buf] + (size_t)(tid + 256 * i) * 16);
        }
    };

    f32x4 acc[4][4] = {};
    int nt = K / BK;
    stage(0, 0);
    __syncthreads();
    for (int t = 0; t < nt; ++t) {
        int cur = t & 1;
        if (t + 1 < nt) stage(cur ^ 1, (t + 1) * BK);
        const char* Ab = (const char*)As[cur];
        const char* Bp = (const char*)Bs[cur];
        #pragma unroll
        for (int s = 0; s < 2; ++s) {
            int koff = s * 64 + g16;
            bf16x8 af[4], bw[4];
            #pragma unroll
            for (int f = 0; f < 4; ++f) {
                int ar = wr + f * 16 + lr;
                af[f] = *(const bf16x8*)(Ab + ar * 128 + (koff ^ sw));
                int br = wc + f * 16 + lr;
                bw[f] = *(const bf16x8*)(Bp + br * 128 + (koff ^ sw));
            }
            #pragma unroll
            for (int f = 0; f < 4; ++f)
                #pragma unroll
                for (int j = 0; j < 4; ++j)
                    acc[f][j] = __builtin_amdgcn_mfma_f32_16x16x32_bf16(
                        af[f], bw[j], acc[f][j], 0, 0, 0);
        }
        __syncthreads();
    }

    int g4 = (lane >> 4) * 4;
    #pragma unroll
    for (int f = 0; f < 4; ++f) {
        #pragma unroll
        for (int j = 0; j < 4; ++j) {
            int col = bn + wc + j * 16 + lr;
            #pragma unroll
            for (int r = 0; r < 4; ++r) {
                int rr = bm + wr + f * 16 + g4 + r;
                size_t idx = (size_t)rr * N + col;
                float v = acc[f][j][r];
                if (EPI == 1) {
                    ((unsigned short*)Cv)[idx] = f2b(gelu_tanh(v + bias[col]));
                } else if (EPI == 2) {
                    ((float*)Cv)[idx] += v + bias[col];
                } else if (EPI == 3) {
                    ((float*)Cv)[idx] = v + extra[(size_t)(rr / batch_rows) * N + col];
                } else if (EPI == 4) {
                    ((unsigned short*)Cv)[idx] = f2b(v);
                } else if (EPI == 5) {
                    ((unsigned short*)Cv)[(size_t)col * ldo + rr] = f2b(v);
                }
            }
        }
    }
}

// ---------------- k column-softmax stats (softmax over sequence dim) ----------------
__global__ __launch_bounds__(256) void ksm_stats1(
    const unsigned short* __restrict__ k, float* __restrict__ pm, float* __restrict__ ps) {
    int b = blockIdx.y, rb = blockIdx.x;
    const unsigned short* kp = k + ((size_t)b * NN + (size_t)rb * 128) * DIMC;
    int t = threadIdx.x;
    float m0 = -1e30f, s0 = 0.f, m1 = -1e30f, s1 = 0.f;
    for (int r = 0; r < 128; ++r) {
        float x0 = b2f(kp[(size_t)r * DIMC + t]);
        float x1 = b2f(kp[(size_t)r * DIMC + t + 256]);
        if (x0 > m0) { s0 = s0 * __expf(m0 - x0) + 1.f; m0 = x0; } else s0 += __expf(x0 - m0);
        if (x1 > m1) { s1 = s1 * __expf(m1 - x1) + 1.f; m1 = x1; } else s1 += __expf(x1 - m1);
    }
    size_t base = ((size_t)b * 64 + rb) * DIMC;
    pm[base + t] = m0; pm[base + t + 256] = m1;
    ps[base + t] = s0; ps[base + t + 256] = s1;
}

__global__ void ksm_stats2(const float* __restrict__ pm, const float* __restrict__ ps,
                           float* __restrict__ Mst, float* __restrict__ Sinv) {
    int idx = blockIdx.x * 256 + threadIdx.x;
    int b = idx >> 9, c = idx & 511;
    float m = -1e30f, s = 0.f;
    for (int rb = 0; rb < 64; ++rb) {
        float mm = pm[((size_t)b * 64 + rb) * DIMC + c];
        float ss = ps[((size_t)b * 64 + rb) * DIMC + c];
        if (mm > m) { s = s * __expf(m - mm) + ss; m = mm; } else s += ss * __expf(mm - m);
    }
    Mst[idx] = m;
    Sinv[idx] = 1.f / s;
}

// ---------------- context = sum_n expk[n,d] * v[n,e] ----------------
__global__ __launch_bounds__(256) void context_kernel(
    const unsigned short* __restrict__ kb, const unsigned short* __restrict__ vb,
    const float* __restrict__ Mst, const float* __restrict__ Sinv,
    float* __restrict__ ctx) {
    int b = blockIdx.z, hd = blockIdx.y, rb = blockIdx.x;  // rb < 16 (512 rows each)
    int tid = threadIdx.x, tx = tid & 15, ty = tid >> 4;
    __shared__ float kx[64][68];
    __shared__ float vx[64][68];
    int r0t = tid >> 3;            // 0..31
    int c8 = (tid & 7) * 8;
    int cb = hd * 64 + c8;
    float mv[8], sv[8];
    #pragma unroll
    for (int j = 0; j < 8; ++j) { mv[j] = Mst[b * DIMC + cb + j]; sv[j] = Sinv[b * DIMC + cb + j]; }
    float cacc[4][4] = {};
    for (int sub = 0; sub < 8; ++sub) {
        size_t row0 = (size_t)b * NN + (size_t)rb * 512 + sub * 64;
        #pragma unroll
        for (int i = 0; i < 2; ++i) {
            int r = r0t + i * 32;
            us8 kv = *(const us8*)(kb + (row0 + r) * DIMC + cb);
            us8 vv = *(const us8*)(vb + (row0 + r) * DIMC + cb);
            #pragma unroll
            for (int j = 0; j < 8; ++j) {
                kx[r][c8 + j] = __expf(b2f(kv[j]) - mv[j]) * sv[j];
                vx[r][c8 + j] = b2f(vv[j]);
            }
        }
        __syncthreads();
        #pragma unroll 4
        for (int r = 0; r < 64; ++r) {
            float4 a4 = *(const float4*)&kx[r][ty * 4];
            float4 b4 = *(const float4*)&vx[r][tx * 4];
            float av[4] = {a4.x, a4.y, a4.z, a4.w};
            float bv[4] = {b4.x, b4.y, b4.z, b4.w};
            #pragma unroll
            for (int i = 0; i < 4; ++i)
                #pragma unroll
                for (int j = 0; j < 4; ++j)
                    cacc[i][j] = fmaf(av[i], bv[j], cacc[i][j]);
        }
        __syncthreads();
    }
    size_t cbase = (size_t)(b * HEADS + hd) * 64 * 64;
    #pragma unroll
    for (int i = 0; i < 4; ++i)
        #pragma unroll
        for (int j = 0; j < 4; ++j)
            atomicAdd(&ctx[cbase + (size_t)(ty * 4 + i) * 64 + tx * 4 + j], cacc[i][j]);
}

// ---------------- q feature-softmax in place (bf16) ----------------
__global__ __launch_bounds__(256) void qsm_kernel(unsigned short* __restrict__ qb) {
    int lane = threadIdx.x & 63;
    size_t row = (size_t)blockIdx.x * 4 + (threadIdx.x >> 6);
    size_t base = row * DIMC;
    #pragma unroll
    for (int h = 0; h < 8; ++h) {
        float v = b2f(qb[base + h * 64 + lane]);
        float m = v;
        #pragma unroll
        for (int o = 32; o; o >>= 1) m = fmaxf(m, __shfl_xor(m, o, 64));
        float e = __expf(v - m);
        float s = e;
        #pragma unroll
        for (int o = 32; o; o >>= 1) s += __shfl_xor(s, o, 64);
        qb[base + h * 64 + lane] = f2b(e * (0.125f / s));
    }
}

// ---------------- caw[b][h*64+d][n] = sum_e ctx[b][h][d][e] * aow[h*64+e][n] ----------------
__global__ __launch_bounds__(256) void caw_kernel(const float* __restrict__ ctx,
                                                  const float* __restrict__ aow,
                                                  float* __restrict__ caw) {
    int nt = blockIdx.x, hd = blockIdx.y, b = blockIdx.z;
    int tid = threadIdx.x, tx = tid & 15, ty = tid >> 4;
    __shared__ float cs[64][68];
    __shared__ float aw[64][68];
    #pragma unroll
    for (int i = 0; i < 4; ++i) {
        int idx = tid + 256 * i;
        int r = idx >> 4, c4 = (idx & 15) * 4;
        *(float4*)&cs[r][c4] = *(const float4*)(ctx + ((size_t)(b * HEADS + hd) * 64 + r) * 64 + c4);
        *(float4*)&aw[r][c4] = *(const float4*)(aow + (size_t)(hd * 64 + r) * DIMC + nt * 64 + c4);
    }
    __syncthreads();
    float acc[4][4] = {};
    for (int e = 0; e < 64; ++e) {
        float av[4];
        #pragma unroll
        for (int i = 0; i < 4; ++i) av[i] = cs[ty * 4 + i][e];
        float4 b4 = *(const float4*)&aw[e][tx * 4];
        float bv[4] = {b4.x, b4.y, b4.z, b4.w};
        #pragma unroll
        for (int i = 0; i < 4; ++i)
            #pragma unroll
            for (int j = 0; j < 4; ++j)
                acc[i][j] = fmaf(av[i], bv[j], acc[i][j]);
    }
    #pragma unroll
    for (int i = 0; i < 4; ++i)
        #pragma unroll
        for (int j = 0; j < 4; ++j)
            caw[(size_t)b * DIMC * DIMC + (size_t)(hd * 64 + ty * 4 + i) * DIMC + nt * 64 + tx * 4 + j]
                = acc[i][j];
}

// ---------------- pos head ----------------
__global__ __launch_bounds__(256) void pos_kernel(
    const float* __restrict__ x, const float* __restrict__ w,
    const float* __restrict__ b2, float* __restrict__ out) {
    int lane = threadIdx.x & 63;
    size_t row = (size_t)blockIdx.x * 4 + (threadIdx.x >> 6);
    const float* xp = x + row * DIMC;
    float acc0 = 0.f, acc1 = 0.f;
    #pragma unroll
    for (int i = 0; i < 2; ++i) {
        float4 xv = *(const float4*)(xp + lane * 8 + i * 4);
        const float* wp = w + (size_t)(lane * 8 + i * 4) * 2;
        float4 w0 = *(const float4*)(wp);
        float4 w1 = *(const float4*)(wp + 4);
        acc0 += xv.x * w0.x + xv.y * w0.z + xv.z * w1.x + xv.w * w1.z;
        acc1 += xv.x * w0.y + xv.y * w0.w + xv.z * w1.y + xv.w * w1.w;
    }
    #pragma unroll
    for (int o = 32; o; o >>= 1) { acc0 += __shfl_down(acc0, o, 64); acc1 += __shfl_down(acc1, o, 64); }
    if (lane == 0) {
        out[row * 2] = acc0 + b2[0];
        out[row * 2 + 1] = acc1 + b2[1];
    }
}

// ---------------- launch ----------------
extern "C" void kernel_launch(void* const* d_in, const int* in_sizes, int n_in,
                              void* d_out, int out_size, void* d_ws, size_t ws_size,
                              hipStream_t stream) {
    (void)in_sizes; (void)n_in; (void)out_size; (void)ws_size;
    const float* nf  = (const float*)d_in[0];
    const float* dt  = (const float*)d_in[1];
    const float* pos = (const float*)d_in[2];
    const float* msk = (const float*)d_in[3];
    const float* yyw = (const float*)d_in[4];
    const float* yyb = (const float*)d_in[5];
    const float* p1w = (const float*)d_in[6];
    const float* p1b = (const float*)d_in[7];
    const float* p2w = (const float*)d_in[8];
    const float* p2b = (const float*)d_in[9];
    const float* lxw = (const float*)d_in[10];
    const float* lxb = (const float*)d_in[11];
    const float* cw  = (const float*)d_in[12];
    const float* cb  = (const float*)d_in[13];
    const float* l1g = (const float*)d_in[14];
    const float* l1b = (const float*)d_in[15];
    const float* qw  = (const float*)d_in[16];
    const float* kw  = (const float*)d_in[17];
    const float* vw  = (const float*)d_in[18];
    const float* aow = (const float*)d_in[19];
    const float* aob = (const float*)d_in[20];
    const float* l2g = (const float*)d_in[21];
    const float* l2b = (const float*)d_in[22];
    const float* f1w = (const float*)d_in[23];
    const float* f1b = (const float*)d_in[24];
    const float* f2w = (const float*)d_in[25];
    const float* f2b_ = (const float*)d_in[26];
    const float* hpw = (const float*)d_in[27];
    const float* hpb = (const float*)d_in[28];

    float* ws = (float*)d_ws;
    // R0: catA -> hb ; caw in tail slack
    unsigned short* catA_u  = (unsigned short*)(ws + OFF_R0);
    unsigned short* hb_u    = (unsigned short*)(ws + OFF_R0);
    float*          caw     = ws + OFF_CAW;
    // R1: kb -> qb -> mid
    unsigned short* kb_u    = (unsigned short*)(ws + OFF_R1);
    unsigned short* qb_u    = (unsigned short*)(ws + OFF_R1);
    unsigned short* mid_u   = (unsigned short*)(ws + OFF_R1);
    // R2: vb -> cawT
    unsigned short* vb_u    = (unsigned short*)(ws + OFF_R2);
    unsigned short* cawT_u  = (unsigned short*)(ws + OFF_R2);
    unsigned short* catWT_u = (unsigned short*)(ws + OFF_CATWT);
    unsigned short* kwT_u   = (unsigned short*)(ws + OFF_KWT);
    unsigned short* vwT_u   = (unsigned short*)(ws + OFF_VWT);
    unsigned short* qwT_u   = (unsigned short*)(ws + OFF_QWT);
    unsigned short* f1wT_u  = (unsigned short*)(ws + OFF_F1WT);
    unsigned short* f2wT_u  = (unsigned short*)(ws + OFF_F2WT);
    unsigned short* lxwb_u  = (unsigned short*)(ws + OFF_LXWB);
    unsigned short* cw0T_u  = (unsigned short*)(ws + OFF_CW0T);
    float* yv   = ws + OFF_Y;
    float* bbf  = ws + OFF_BB;
    float* pm   = ws + OFF_PM;
    float* ps2  = ws + OFF_PS;
    float* Mst  = ws + OFF_M;
    float* Sinv = ws + OFF_SINV;
    float* ctx  = ws + OFF_CTX;

    float* xout = (float*)d_out;
    float* yout = xout + (size_t)ROWS * DIMC;
    float* pout = yout + NB * DT;

    // prologue scalars + weight conversions
    y_kernel<<<4, 128, 0, stream>>>(dt, yyw, yyb, yv, yout);
    bb_kernel<<<8, 256, 0, stream>>>(lxb, cw, cb, yv, bbf);
    conv_bf16<<<128, 256, 0, stream>>>(lxw, lxwb_u, 32768);
    transconv<<<dim3(16, 16), 256, 0, stream>>>(cw, cw0T_u, 512, 512, 512);
    // cw2T into catWT columns 512..575
    transconv<<<dim3(16, 2), 256, 0, stream>>>(cw + (size_t)DIMC * DIMC, catWT_u + 512, 64, 512, KCAT);
    transconv<<<dim3(16, 16), 256, 0, stream>>>(kw, kwT_u, 512, 512, 512);
    transconv<<<dim3(16, 16), 256, 0, stream>>>(vw, vwT_u, 512, 512, 512);
    transconv<<<dim3(16, 16), 256, 0, stream>>>(qw, qwT_u, 512, 512, 512);
    transconv<<<dim3(64, 16), 256, 0, stream>>>(f1w, f1wT_u, 512, 2048, 512);
    transconv<<<dim3(16, 64), 256, 0, stream>>>(f2w, f2wT_u, 2048, 512, 2048);
    conv_bf16_strided<<<8192, 256, 0, stream>>>(nf, catA_u, KCAT);
    delta_kernel<<<8192, 256, 0, stream>>>(pos, msk, p1w, p1b, p2w, p2b, catA_u);

    // catWT cols 0..511 = (lxw @ cw0)^T
    gemm_mfma<5><<<dim3(4, 4), 256, 0, stream>>>(
        lxwb_u, 512, cw0T_u, 512, nullptr, nullptr, 0,
        catWT_u, 512, 512, 512, 0, 0, KCAT);

    // cat = catA @ catWT^T + bb[batch] -> xout (f32)
    gemm_mfma<3><<<dim3(4, 256), 256, 0, stream>>>(
        catA_u, KCAT, catWT_u, KCAT, nullptr, bbf, NN,
        xout, ROWS, 512, KCAT, 0, 0, 0);

    // LN1: xout -> hb (overwrites catA region; catA is dead)
    ln_kernel<<<ROWS, 128, 0, stream>>>(xout, hb_u, l1g, l1b);

    // k, v projections (bf16 out)
    gemm_mfma<4><<<dim3(4, 256), 256, 0, stream>>>(
        hb_u, 512, kwT_u, 512, nullptr, nullptr, 0,
        kb_u, ROWS, 512, 512, 0, 0, 0);
    gemm_mfma<4><<<dim3(4, 256), 256, 0, stream>>>(
        hb_u, 512, vwT_u, 512, nullptr, nullptr, 0,
        vb_u, ROWS, 512, 512, 0, 0, 0);

    // k sequence-softmax stats
    ksm_stats1<<<dim3(64, 4), 256, 0, stream>>>(kb_u, pm, ps2);
    ksm_stats2<<<8, 256, 0, stream>>>(pm, ps2, Mst, Sinv);

    // context (consumes kb, vb -> both dead after)
    hipMemsetAsync(ctx, 0, (size_t)NB * HEADS * 64 * 64 * sizeof(float), stream);
    context_kernel<<<dim3(16, HEADS, NB), 256, 0, stream>>>(kb_u, vb_u, Mst, Sinv, ctx);

    // q projection into R1 (kb dead), softmax in place
    gemm_mfma<4><<<dim3(4, 256), 256, 0, stream>>>(
        hb_u, 512, qwT_u, 512, nullptr, nullptr, 0,
        qb_u, ROWS, 512, 512, 0, 0, 0);
    qsm_kernel<<<8192, 256, 0, stream>>>(qb_u);

    // compose ctx with attn_out_w per batch; transpose into R2 (vb dead)
    caw_kernel<<<dim3(8, 8, 4), 256, 0, stream>>>(ctx, aow, caw);
    for (int b = 0; b < NB; ++b)
        transconv<<<dim3(16, 16), 256, 0, stream>>>(caw + (size_t)b * 262144,
                                                    cawT_u + (size_t)b * 262144, 512, 512, 512);

    // x += qsm @ caw[b]^T + aob  (per-batch B)
    gemm_mfma<2><<<dim3(4, 256), 256, 0, stream>>>(
        qb_u, 512, cawT_u, 512, aob, nullptr, 0,
        xout, ROWS, 512, 512, 262144, NN, 0);

    // FF block (hb reused for LN2; mid in R1, qb dead)
    ln_kernel<<<ROWS, 128, 0, stream>>>(xout, hb_u, l2g, l2b);
    for (int b = 0; b < NB; ++b) {
        gemm_mfma<1><<<dim3(16, 64), 256, 0, stream>>>(
            hb_u + (size_t)b * NN * DIMC, 512, f1wT_u, 512, f1b, nullptr, 0,
            mid_u, NN, FF, 512, 0, 0, 0);
        gemm_mfma<2><<<dim3(4, 64), 256, 0, stream>>>(
            mid_u, 2048, f2wT_u, 2048, f2b_, nullptr, 0,
            xout + (size_t)b * NN * DIMC, NN, 512, 2048, 0, 0, 0);
    }

    pos_kernel<<<8192, 256, 0, stream>>>(xout, hpw, hpb, pout);
}